// Round 14
// baseline (2842.738 us; speedup 1.0000x reference)
//
#include <hip/hip_runtime.h>
#include <hip/hip_bf16.h>

#define BB 16
#define NPTS 1024
#define KNB 20
#define HC 512

__device__ __forceinline__ float XV(const float* __restrict__ X, int b, int n, int c)
{
    return X[((size_t)b * NPTS + n) * 3 + c];
}

__device__ __forceinline__ unsigned long long dist2key(float d, int m)
{
    unsigned u = __float_as_uint(d);
    u = (u & 0x80000000u) ? ~u : (u | 0x80000000u);
    return ((unsigned long long)u << 32) | (unsigned)(1023 - m);
}

__device__ __forceinline__ void wave_topk_write(unsigned long long* key,
                                                int* __restrict__ idxo,
                                                size_t obase, int lane)
{
    for (int it = 0; it < KNB; ++it) {
        unsigned long long best = 0ull; int bj = -1;
#pragma unroll
        for (int j = 0; j < 16; ++j) if (key[j] > best) { best = key[j]; bj = j; }
        unsigned long long wbest = best;
        for (int off = 32; off > 0; off >>= 1) {
            const unsigned long long o = __shfl_down(wbest, off, 64);
            if (o > wbest) wbest = o;
        }
        wbest = __shfl(wbest, 0, 64);
        if (best == wbest && bj >= 0) key[bj] = 0ull;
        if (lane == 0) idxo[obase + it] = 1023 - (int)(wbest & 0xFFFFFFFFull);
    }
}

__global__ void sentinel_kernel(float* __restrict__ out, float val)
{
    const int i = blockIdx.x * 256 + threadIdx.x;
    if (i < BB * 40) out[i] = val;
}

// ---------------- squared norms ----------------
__global__ void xx_kernel(const float* __restrict__ H, const float* __restrict__ X,
                          float* __restrict__ xx, int cin, int off_in, int use_x)
{
    const int p = blockIdx.x * blockDim.x + threadIdx.x;
    if (p >= BB * NPTS) return;
    float s = 0.f;
    if (use_x) {
        const int b = p >> 10, n = p & 1023;
        for (int c = 0; c < 3; ++c) { const float v = XV(X, b, n, c); s += v * v; }
    } else {
        const float4* r4 = (const float4*)(H + (size_t)p * HC + off_in);
        for (int c4 = 0; c4 < cin / 4; ++c4) {
            const float4 v = r4[c4];
            s += v.x*v.x + v.y*v.y + v.z*v.z + v.w*v.w;
        }
    }
    xx[p] = s;
}

// ---------------- knn (round-11 verified) ----------------
template<int CIN, bool USEX>
__global__ __launch_bounds__(256) void knn_kernel(
    const float* __restrict__ H, const float* __restrict__ X, const float* __restrict__ xx,
    int* __restrict__ idxo, int off_in)
{
    __shared__ __align__(16) float qv[CIN < 4 ? 4 : CIN];
    __shared__ float dist[NPTS];
    const int blk = blockIdx.x;
    const int b = blk >> 10, q = blk & 1023;
    const int tid = threadIdx.x;
    const int base = b * NPTS;

    if (USEX) {
        if (tid < 3) qv[tid] = XV(X, b, q, tid);
    } else {
        for (int c = tid; c < CIN; c += 256) qv[c] = H[(size_t)(base + q) * HC + off_in + c];
    }
    __syncthreads();
    const float xxq = xx[base + q];

    if (USEX) {
        for (int j = 0; j < 4; ++j) {
            const int m = tid + 256 * j;
            const float acc = qv[0]*XV(X,b,m,0) + qv[1]*XV(X,b,m,1) + qv[2]*XV(X,b,m,2);
            dist[m] = (2.f * acc - xxq) - xx[base + m];
        }
    } else {
        const int g = tid >> 3, l = tid & 7;
        for (int it = 0; it < 32; ++it) {
            const int m = g + 32 * it;
            const float4* rm4 = (const float4*)(H + (size_t)(base + m) * HC + off_in);
            float acc = 0.f;
#pragma unroll
            for (int r = 0; r < CIN / 32; ++r) {
                const int c4 = l + 8 * r;
                const float4 v = rm4[c4];
                const float4 a = *(const float4*)&qv[4 * c4];
                acc += a.x*v.x + a.y*v.y + a.z*v.z + a.w*v.w;
            }
            acc += __shfl_xor(acc, 1, 64);
            acc += __shfl_xor(acc, 2, 64);
            acc += __shfl_xor(acc, 4, 64);
            if (l == 0) dist[m] = (2.f * acc - xxq) - xx[base + m];
        }
    }
    __syncthreads();

    if (tid < 64) {
        const int lane = tid;
        unsigned long long key[16];
#pragma unroll
        for (int j = 0; j < 16; ++j) {
            const int m = lane + 64 * j;
            key[j] = dist2key(dist[m], m);
        }
        wave_topk_write(key, idxo, (size_t)(base + q) * KNB, lane);
    }
}

// weight fetch for gemm_conv: row og of [W1; W2-W1]
__device__ __forceinline__ float4 wfetch(const float* __restrict__ W, int og,
                                         int CIN, int COUT, int c0)
{
    if (og < COUT) return *(const float4*)(W + (size_t)og * 2 * CIN + c0);
    const float* r0 = W + (size_t)(og - COUT) * 2 * CIN;
    const float4 a = *(const float4*)(r0 + c0);
    const float4 b = *(const float4*)(r0 + CIN + c0);
    return make_float4(b.x - a.x, b.y - a.y, b.z - a.z, b.w - a.w);
}

// ---------------- P GEMM: 64 rows x 128 cols, 2 outputs x 16 rows per thread ----------------
__global__ __launch_bounds__(256, 4) void gemm_conv_kernel(
    const float* __restrict__ H, const float* __restrict__ W, float* __restrict__ P,
    int off_in, int CIN, int COUT, int NO128)
{
    __shared__ float hl[32][68];          // [c][n], 64 rows + pad
    const int mblk = blockIdx.x / NO128;
    const int oblk = blockIdx.x - mblk * NO128;
    const int tid = threadIdx.x;
    const int o = tid & 63, grp = tid >> 6;   // grp owns rows [grp*16, grp*16+16)
    const int NO = NO128 * 128;
    const int n0 = mblk * 64;
    const int og0 = oblk * 128 + o;
    const int og1 = og0 + 64;

    float acc0[16], acc1[16];
#pragma unroll
    for (int i = 0; i < 16; ++i) { acc0[i] = 0.f; acc1[i] = 0.f; }

    for (int ct = 0; ct < CIN / 32; ++ct) {
        for (int r = 0; r < 2; ++r) {
            const int e = tid + 256 * r;           // 0..511 float4s
            const int n = e & 63, c4 = e >> 6;
            const float4 hv = *(const float4*)(H + (size_t)(n0 + n) * HC + off_in + ct * 32 + c4 * 4);
            hl[c4*4+0][n] = hv.x; hl[c4*4+1][n] = hv.y; hl[c4*4+2][n] = hv.z; hl[c4*4+3][n] = hv.w;
        }
        __syncthreads();
        for (int r = 0; r < 8; ++r) {
            const float4 wa = wfetch(W, og0, CIN, COUT, ct * 32 + r * 4);
            const float4 wb = wfetch(W, og1, CIN, COUT, ct * 32 + r * 4);
            const float was[4] = {wa.x, wa.y, wa.z, wa.w};
            const float wbs[4] = {wb.x, wb.y, wb.z, wb.w};
#pragma unroll
            for (int j = 0; j < 4; ++j) {
                const float wva = was[j], wvb = wbs[j];
                const float* hr = &hl[r * 4 + j][grp * 16];
#pragma unroll
                for (int nn = 0; nn < 4; ++nn) {
                    const float4 hv = *(const float4*)(hr + 4 * nn);
                    acc0[4*nn+0] += wva * hv.x; acc0[4*nn+1] += wva * hv.y;
                    acc0[4*nn+2] += wva * hv.z; acc0[4*nn+3] += wva * hv.w;
                    acc1[4*nn+0] += wvb * hv.x; acc1[4*nn+1] += wvb * hv.y;
                    acc1[4*nn+2] += wvb * hv.z; acc1[4*nn+3] += wvb * hv.w;
                }
            }
        }
        __syncthreads();
    }

#pragma unroll
    for (int i = 0; i < 16; ++i) {
        P[(size_t)(n0 + grp * 16 + i) * NO + og0] = acc0[i];
        P[(size_t)(n0 + grp * 16 + i) * NO + og1] = acc1[i];
    }
}

// epilogue: y[q,k] = P1[nb] + P2[q]; BN+lrelu+max over k
template<int COUT>
__global__ __launch_bounds__(COUT) void edge_epi_kernel(
    const float* __restrict__ P, const int* __restrict__ idx,
    const float* __restrict__ Bs, const float* __restrict__ G, const float* __restrict__ Be,
    const float* __restrict__ Bm, const float* __restrict__ Bv,
    float* __restrict__ Hout, int off_out)
{
    constexpr int NO = 2 * COUT;
    const int blk = blockIdx.x;
    const int base = (blk >> 10) << 10;
    const int o = threadIdx.x;
    const float s = G[o] / sqrtf(Bv[o] + 1e-5f);
    const float beo = Be[o];
    const float cb = P[(size_t)blk * NO + COUT + o] + Bs[o] - Bm[o];
    float mx = -INFINITY;
    for (int k = 0; k < KNB; ++k) {
        const int m = idx[(size_t)blk * KNB + k];
        const float v = P[(size_t)(base + m) * NO + o];
        float t = (v + cb) * s + beo;
        t = t > 0.f ? t : 0.2f * t;
        mx = fmaxf(mx, t);
    }
    Hout[(size_t)blk * HC + off_out + o] = mx;
}

// ---------------- fallback conv (round-11) ----------------
template<int CIN, int COUT, int OPO, bool USEX>
__global__ __launch_bounds__(COUT / OPO) void conv_kernel(
    const float* __restrict__ H, const float* __restrict__ X, const int* __restrict__ idx,
    const float* __restrict__ W, const float* __restrict__ Bs, const float* __restrict__ G,
    const float* __restrict__ Be, const float* __restrict__ Bm, const float* __restrict__ Bv,
    float* __restrict__ Hout, int off_in, int off_out)
{
    constexpr int TPB = COUT / OPO;
    __shared__ __align__(16) float ctr[CIN];
    __shared__ __align__(16) float nb[KNB][CIN];
    __shared__ int sidx[KNB];
    const int blk = blockIdx.x;
    const int b = blk >> 10, q = blk & 1023;
    const int tid = threadIdx.x;
    const int base = b * NPTS;

    if (tid < KNB) sidx[tid] = idx[(size_t)(base + q) * KNB + tid];
    for (int c = tid; c < CIN; c += TPB)
        ctr[c] = USEX ? XV(X, b, q, c) : H[(size_t)(base + q) * HC + off_in + c];
    __syncthreads();
    if constexpr (CIN % 4 == 0) {
        constexpr int CIN4 = CIN / 4;
        for (int t = tid; t < KNB * CIN4; t += TPB) {
            const int k = t / CIN4, c4 = t - k * CIN4;
            ((float4*)nb[k])[c4] = *(const float4*)(H + (size_t)(base + sidx[k]) * HC + off_in + 4 * c4);
        }
    } else {
        for (int t = tid; t < KNB * CIN; t += TPB) {
            const int k = t / CIN, c = t - k * CIN;
            nb[k][c] = USEX ? XV(X, b, sidx[k], c) : H[(size_t)(base + sidx[k]) * HC + off_in + c];
        }
    }
    __syncthreads();

    float acc[OPO][KNB];
    float cacc[OPO];
#pragma unroll
    for (int p = 0; p < OPO; ++p) {
        cacc[p] = 0.f;
#pragma unroll
        for (int k = 0; k < KNB; ++k) acc[p][k] = 0.f;
    }

    if constexpr (CIN % 4 == 0) {
        constexpr int CIN4 = CIN / 4;
        const float4* w4[OPO];
#pragma unroll
        for (int p = 0; p < OPO; ++p)
            w4[p] = (const float4*)(W + (size_t)(tid + p * TPB) * 2 * CIN);
        for (int c4 = 0; c4 < CIN4; ++c4) {
            const float4 cv = *(const float4*)&ctr[4 * c4];
            float4 w1[OPO];
#pragma unroll
            for (int p = 0; p < OPO; ++p) {
                w1[p] = w4[p][c4];
                const float4 w2 = w4[p][CIN4 + c4];
                cacc[p] += (w2.x - w1[p].x) * cv.x + (w2.y - w1[p].y) * cv.y
                         + (w2.z - w1[p].z) * cv.z + (w2.w - w1[p].w) * cv.w;
            }
#pragma unroll
            for (int k = 0; k < KNB; ++k) {
                const float4 nv = *(const float4*)&nb[k][4 * c4];
#pragma unroll
                for (int p = 0; p < OPO; ++p)
                    acc[p][k] += w1[p].x * nv.x + w1[p].y * nv.y + w1[p].z * nv.z + w1[p].w * nv.w;
            }
        }
    } else {
        const float* wr = W + (size_t)tid * 2 * CIN;
        for (int c = 0; c < CIN; ++c) {
            const float w1 = wr[c], w2 = wr[CIN + c];
            cacc[0] += (w2 - w1) * ctr[c];
#pragma unroll
            for (int k = 0; k < KNB; ++k) acc[0][k] += w1 * nb[k][c];
        }
    }

#pragma unroll
    for (int p = 0; p < OPO; ++p) {
        const int o = tid + p * TPB;
        const float s = G[o] / sqrtf(Bv[o] + 1e-5f);
        const float beo = Be[o];
        const float cb = cacc[p] + Bs[o] - Bm[o];
        float mx = -INFINITY;
#pragma unroll
        for (int k = 0; k < KNB; ++k) {
            float t = (acc[p][k] + cb) * s + beo;
            t = t > 0.f ? t : 0.2f * t;
            mx = fmaxf(mx, t);
        }
        Hout[(size_t)(base + q) * HC + off_out + o] = mx;
    }
}

// ---------------- lc conv + pool: 64 n x 128 o per block, 2 outputs x 16 rows/thread ----------------
__global__ __launch_bounds__(256, 4) void lcpool_kernel(
    const float* __restrict__ H, const float* __restrict__ W, const float* __restrict__ Bs,
    const float* __restrict__ G, const float* __restrict__ Be,
    const float* __restrict__ Bm, const float* __restrict__ Bv,
    float* __restrict__ pmax, float* __restrict__ psum)
{
    __shared__ float hl[32][68];
    __shared__ float redm[4][128];
    __shared__ float reds[4][128];
    const int bid = blockIdx.x;            // BB * 8 * 16
    const int b = bid >> 7;
    const int rem = bid & 127;
    const int oblk = rem >> 4;             // 0..7  (128 o each)
    const int nblk = rem & 15;             // 0..15 (64 n each)
    const int tid = threadIdx.x;
    const int o = tid & 63;
    const int grp = tid >> 6;
    const int og0 = oblk * 128 + o;
    const int og1 = og0 + 64;
    const int n0 = nblk * 64;
    const size_t hbase = (size_t)b * NPTS * HC;
    const float4* wa4 = (const float4*)(W + (size_t)og0 * HC);
    const float4* wb4 = (const float4*)(W + (size_t)og1 * HC);

    float acc0[16], acc1[16];
#pragma unroll
    for (int i = 0; i < 16; ++i) { acc0[i] = 0.f; acc1[i] = 0.f; }

    for (int ct = 0; ct < 16; ++ct) {
        for (int r = 0; r < 2; ++r) {
            const int e = tid + 256 * r;
            const int n = e & 63, c4 = e >> 6;
            const float4 hv = *(const float4*)(H + hbase + (size_t)(n0 + n) * HC + ct * 32 + c4 * 4);
            hl[c4*4+0][n] = hv.x; hl[c4*4+1][n] = hv.y; hl[c4*4+2][n] = hv.z; hl[c4*4+3][n] = hv.w;
        }
        __syncthreads();
        for (int r = 0; r < 8; ++r) {
            const float4 wa = wa4[ct * 8 + r];
            const float4 wb = wb4[ct * 8 + r];
            const float was[4] = {wa.x, wa.y, wa.z, wa.w};
            const float wbs[4] = {wb.x, wb.y, wb.z, wb.w};
#pragma unroll
            for (int j = 0; j < 4; ++j) {
                const float wva = was[j], wvb = wbs[j];
                const float* hr = &hl[r * 4 + j][grp * 16];
#pragma unroll
                for (int nn = 0; nn < 4; ++nn) {
                    const float4 hv = *(const float4*)(hr + 4 * nn);
                    acc0[4*nn+0] += wva * hv.x; acc0[4*nn+1] += wva * hv.y;
                    acc0[4*nn+2] += wva * hv.z; acc0[4*nn+3] += wva * hv.w;
                    acc1[4*nn+0] += wvb * hv.x; acc1[4*nn+1] += wvb * hv.y;
                    acc1[4*nn+2] += wvb * hv.z; acc1[4*nn+3] += wvb * hv.w;
                }
            }
        }
        __syncthreads();
    }

#pragma unroll
    for (int p = 0; p < 2; ++p) {
        const int og = p ? og1 : og0;
        const float* acc = p ? acc1 : acc0;
        const float s = G[og] / sqrtf(Bv[og] + 1e-5f);
        const float beo = Be[og];
        const float mb = Bs[og] - Bm[og];
        float pm = -INFINITY, ps = 0.f;
#pragma unroll
        for (int i = 0; i < 16; ++i) {
            float t = (acc[i] + mb) * s + beo;
            t = t > 0.f ? t : 0.2f * t;
            pm = fmaxf(pm, t); ps += t;
        }
        redm[grp][o + 64 * p] = pm; reds[grp][o + 64 * p] = ps;
    }
    __syncthreads();
    if (grp == 0) {
#pragma unroll
        for (int p = 0; p < 2; ++p) {
            const int oo = o + 64 * p;
            float m0 = redm[0][oo], s0 = reds[0][oo];
            for (int i2 = 1; i2 < 4; ++i2) { m0 = fmaxf(m0, redm[i2][oo]); s0 += reds[i2][oo]; }
            pmax[((size_t)b * 16 + nblk) * 1024 + oblk * 128 + oo] = m0;
            psum[((size_t)b * 16 + nblk) * 1024 + oblk * 128 + oo] = s0;
        }
    }
}

__global__ void pool_reduce_kernel(const float* __restrict__ pmax, const float* __restrict__ psum,
                                   float* __restrict__ h2)
{
    const int i = blockIdx.x * 256 + threadIdx.x;
    if (i >= BB * 1024) return;
    const int b = i >> 10, o = i & 1023;
    float mx = -INFINITY, sm = 0.f;
    for (int c = 0; c < 16; ++c) {
        mx = fmaxf(mx, pmax[((size_t)b * 16 + c) * 1024 + o]);
        sm += psum[((size_t)b * 16 + c) * 1024 + o];
    }
    h2[(size_t)b * 2048 + o] = mx;
    h2[(size_t)b * 2048 + 1024 + o] = sm * (1.f / 1024.f);
}

// ---------------- FC head ----------------
__global__ void l0_kernel(const float* __restrict__ h2, const float* __restrict__ W,
                          const float* __restrict__ G, const float* __restrict__ Be,
                          const float* __restrict__ Bm, const float* __restrict__ Bv,
                          float* __restrict__ h3)
{
    const int i = blockIdx.x * 256 + threadIdx.x;
    if (i >= BB * 512) return;
    const int b = i >> 9, o = i & 511;
    const float4* w4 = (const float4*)(W + (size_t)o * 2048);
    const float4* h4p = (const float4*)(h2 + (size_t)b * 2048);
    float acc = 0.f;
    for (int c = 0; c < 512; ++c) {
        const float4 wv = w4[c]; const float4 hv = h4p[c];
        acc += wv.x*hv.x + wv.y*hv.y + wv.z*hv.z + wv.w*hv.w;
    }
    const float s = G[o] / sqrtf(Bv[o] + 1e-5f);
    float t = (acc - Bm[o]) * s + Be[o];
    t = t > 0.f ? t : 0.2f * t;
    h3[(size_t)b * 512 + o] = t;
}

__global__ void l1_kernel(const float* __restrict__ h3, const float* __restrict__ W,
                          const float* __restrict__ Bs, const float* __restrict__ G,
                          const float* __restrict__ Be, const float* __restrict__ Bm,
                          const float* __restrict__ Bv, float* __restrict__ h4o)
{
    const int i = blockIdx.x * 256 + threadIdx.x;
    if (i >= BB * 256) return;
    const int b = i >> 8, o = i & 255;
    const float4* w4 = (const float4*)(W + (size_t)o * 512);
    const float4* hv4 = (const float4*)(h3 + (size_t)b * 512);
    float acc = 0.f;
    for (int c = 0; c < 128; ++c) {
        const float4 wv = w4[c]; const float4 hv = hv4[c];
        acc += wv.x*hv.x + wv.y*hv.y + wv.z*hv.z + wv.w*hv.w;
    }
    acc += Bs[o];
    const float s = G[o] / sqrtf(Bv[o] + 1e-5f);
    float t = (acc - Bm[o]) * s + Be[o];
    t = t > 0.f ? t : 0.2f * t;
    h4o[(size_t)b * 256 + o] = t;
}

__global__ void out_kernel(const float* __restrict__ h4, const float* __restrict__ W,
                           const float* __restrict__ Bs, float* __restrict__ out)
{
    const int i = blockIdx.x * 256 + threadIdx.x;
    if (i >= BB * 40) return;
    const int b = i / 40, o = i % 40;
    const float4* w4 = (const float4*)(W + (size_t)o * 256);
    const float4* hv4 = (const float4*)(h4 + (size_t)b * 256);
    float acc = 0.f;
    for (int c = 0; c < 64; ++c) {
        const float4 wv = w4[c]; const float4 hv = hv4[c];
        acc += wv.x*hv.x + wv.y*hv.y + wv.z*hv.z + wv.w*hv.w;
    }
    acc += Bs[o];
    out[(size_t)b * 40 + o] = acc;
}

extern "C" void kernel_launch(void* const* d_in, const int* in_sizes, int n_in,
                              void* d_out, int out_size, void* d_ws, size_t ws_size,
                              hipStream_t stream)
{
    static const int expect[44] = {
        49152, 384,64,64,64,64,64, 8192,64,64,64,64,64, 16384,128,128,128,128,128,
        65536,256,256,256,256,256, 524288,1024,1024,1024,1024,1024,
        1048576,512,512,512,512, 131072,256,256,256,256,256, 10240,40};
    int bad = -1;
    if (n_in != 44) bad = 100;
    else if (out_size != BB * 40) bad = 101;
    else {
        for (int i = 0; i < 44; ++i) if (in_sizes[i] != expect[i]) { bad = i; break; }
    }
    if (bad >= 0) {
        sentinel_kernel<<<3, 256, 0, stream>>>((float*)d_out, 500.f + (float)bad);
        return;
    }

    const float* X = (const float*)d_in[0];
    const float *CW[4], *CB[4], *CG[4], *CBE[4], *CM[4], *CV[4];
    for (int i = 0; i < 4; ++i) {
        CW[i]  = (const float*)d_in[1 + 6*i]; CB[i] = (const float*)d_in[2 + 6*i];
        CG[i]  = (const float*)d_in[3 + 6*i]; CBE[i] = (const float*)d_in[4 + 6*i];
        CM[i]  = (const float*)d_in[5 + 6*i]; CV[i] = (const float*)d_in[6 + 6*i];
    }
    const float* LCW = (const float*)d_in[25]; const float* LCB = (const float*)d_in[26];
    const float* LCG = (const float*)d_in[27]; const float* LCBE = (const float*)d_in[28];
    const float* LCM = (const float*)d_in[29]; const float* LCV = (const float*)d_in[30];
    const float* L0W = (const float*)d_in[31]; const float* L0G = (const float*)d_in[32];
    const float* L0BE = (const float*)d_in[33]; const float* L0M = (const float*)d_in[34];
    const float* L0V = (const float*)d_in[35];
    const float* L1W = (const float*)d_in[36]; const float* L1B = (const float*)d_in[37];
    const float* L1G = (const float*)d_in[38]; const float* L1BE = (const float*)d_in[39];
    const float* L1M = (const float*)d_in[40]; const float* L1V = (const float*)d_in[41];
    const float* OW = (const float*)d_in[42]; const float* OB = (const float*)d_in[43];

    float* H    = (float*)d_ws;
    float* XX   = H + (size_t)BB * NPTS * HC;
    int*   IDX  = (int*)(XX + BB * NPTS);
    float* P    = (float*)(IDX + (size_t)BB * NPTS * KNB);
    float* PMAX = P + (size_t)BB * NPTS * 512;
    float* PSUM = PMAX + BB * 16 * 1024;
    float* H2   = PSUM + BB * 16 * 1024;
    float* H3   = H2 + BB * 2048;
    float* H4   = H3 + BB * 512;
    const size_t need_bytes = (size_t)((H4 + BB * 256) - H) * 4;
    const bool use_P = (ws_size >= need_bytes);

    float* fPMAX = P;
    float* fPSUM = fPMAX + BB * 16 * 1024;
    float* fH2   = fPSUM + BB * 16 * 1024;
    float* fH3   = fH2 + BB * 2048;
    float* fH4   = fH3 + BB * 512;

    const int M = BB * NPTS;

    // ---- layer 0 ----
    xx_kernel<<<M/256, 256, 0, stream>>>(H, X, XX, 3, 0, 1);
    knn_kernel<3,true><<<M, 256, 0, stream>>>(H, X, XX, IDX, 0);
    conv_kernel<3,64,1,true><<<M, 64, 0, stream>>>(H, X, IDX,
        CW[0], CB[0], CG[0], CBE[0], CM[0], CV[0], H, 0, 0);

    if (use_P) {
        // ---- layer 1 ----
        xx_kernel<<<M/256, 256, 0, stream>>>(H, X, XX, 64, 0, 0);
        knn_kernel<64,false><<<M, 256, 0, stream>>>(H, X, XX, IDX, 0);
        gemm_conv_kernel<<<(M/64)*1, 256, 0, stream>>>(H, CW[1], P, 0, 64, 64, 1);
        edge_epi_kernel<64><<<M, 64, 0, stream>>>(P, IDX,
            CB[1], CG[1], CBE[1], CM[1], CV[1], H, 64);

        // ---- layer 2 ----
        xx_kernel<<<M/256, 256, 0, stream>>>(H, X, XX, 64, 64, 0);
        knn_kernel<64,false><<<M, 256, 0, stream>>>(H, X, XX, IDX, 64);
        gemm_conv_kernel<<<(M/64)*2, 256, 0, stream>>>(H, CW[2], P, 64, 64, 128, 2);
        edge_epi_kernel<128><<<M, 128, 0, stream>>>(P, IDX,
            CB[2], CG[2], CBE[2], CM[2], CV[2], H, 128);

        // ---- layer 3 ----
        xx_kernel<<<M/256, 256, 0, stream>>>(H, X, XX, 128, 128, 0);
        knn_kernel<128,false><<<M, 256, 0, stream>>>(H, X, XX, IDX, 128);
        gemm_conv_kernel<<<(M/64)*4, 256, 0, stream>>>(H, CW[3], P, 128, 128, 256, 4);
        edge_epi_kernel<256><<<M, 256, 0, stream>>>(P, IDX,
            CB[3], CG[3], CBE[3], CM[3], CV[3], H, 256);

        lcpool_kernel<<<BB*8*16, 256, 0, stream>>>(H, LCW, LCB, LCG, LCBE, LCM, LCV, PMAX, PSUM);
        pool_reduce_kernel<<<BB*1024/256, 256, 0, stream>>>(PMAX, PSUM, H2);
        l0_kernel<<<(BB*512+255)/256, 256, 0, stream>>>(H2, L0W, L0G, L0BE, L0M, L0V, H3);
        l1_kernel<<<(BB*256+255)/256, 256, 0, stream>>>(H3, L1W, L1B, L1G, L1BE, L1M, L1V, H4);
        out_kernel<<<(BB*40+255)/256, 256, 0, stream>>>(H4, OW, OB, (float*)d_out);
    } else {
        xx_kernel<<<M/256, 256, 0, stream>>>(H, X, XX, 64, 0, 0);
        knn_kernel<64,false><<<M, 256, 0, stream>>>(H, X, XX, IDX, 0);
        conv_kernel<64,64,1,false><<<M, 64, 0, stream>>>(H, X, IDX,
            CW[1], CB[1], CG[1], CBE[1], CM[1], CV[1], H, 0, 64);

        xx_kernel<<<M/256, 256, 0, stream>>>(H, X, XX, 64, 64, 0);
        knn_kernel<64,false><<<M, 256, 0, stream>>>(H, X, XX, IDX, 64);
        conv_kernel<64,128,2,false><<<M, 64, 0, stream>>>(H, X, IDX,
            CW[2], CB[2], CG[2], CBE[2], CM[2], CV[2], H, 64, 128);

        xx_kernel<<<M/256, 256, 0, stream>>>(H, X, XX, 128, 128, 0);
        knn_kernel<128,false><<<M, 256, 0, stream>>>(H, X, XX, IDX, 128);
        conv_kernel<128,256,2,false><<<M, 128, 0, stream>>>(H, X, IDX,
            CW[3], CB[3], CG[3], CBE[3], CM[3], CV[3], H, 128, 256);

        lcpool_kernel<<<BB*8*16, 256, 0, stream>>>(H, LCW, LCB, LCG, LCBE, LCM, LCV, fPMAX, fPSUM);
        pool_reduce_kernel<<<BB*1024/256, 256, 0, stream>>>(fPMAX, fPSUM, fH2);
        l0_kernel<<<(BB*512+255)/256, 256, 0, stream>>>(fH2, L0W, L0G, L0BE, L0M, L0V, fH3);
        l1_kernel<<<(BB*256+255)/256, 256, 0, stream>>>(fH3, L1W, L1B, L1G, L1BE, L1M, L1V, fH4);
        out_kernel<<<(BB*40+255)/256, 256, 0, stream>>>(fH4, OW, OB, (float*)d_out);
    }
}

// Round 15
// 1644.817 us; speedup vs baseline: 1.7283x; 1.7283x over previous
//
#include <hip/hip_runtime.h>
#include <hip/hip_bf16.h>

#define BB 16
#define NPTS 1024
#define KNB 20
#define HC 512

__device__ __forceinline__ float XV(const float* __restrict__ X, int b, int n, int c)
{
    return X[((size_t)b * NPTS + n) * 3 + c];
}

__device__ __forceinline__ unsigned long long dist2key(float d, int m)
{
    unsigned u = __float_as_uint(d);
    u = (u & 0x80000000u) ? ~u : (u | 0x80000000u);
    return ((unsigned long long)u << 32) | (unsigned)(1023 - m);
}

__device__ __forceinline__ void wave_topk_write(unsigned long long* key,
                                                int* __restrict__ idxo,
                                                size_t obase, int lane)
{
    for (int it = 0; it < KNB; ++it) {
        unsigned long long best = 0ull; int bj = -1;
#pragma unroll
        for (int j = 0; j < 16; ++j) if (key[j] > best) { best = key[j]; bj = j; }
        unsigned long long wbest = best;
        for (int off = 32; off > 0; off >>= 1) {
            const unsigned long long o = __shfl_down(wbest, off, 64);
            if (o > wbest) wbest = o;
        }
        wbest = __shfl(wbest, 0, 64);
        if (best == wbest && bj >= 0) key[bj] = 0ull;
        if (lane == 0) idxo[obase + it] = 1023 - (int)(wbest & 0xFFFFFFFFull);
    }
}

__global__ void sentinel_kernel(float* __restrict__ out, float val)
{
    const int i = blockIdx.x * 256 + threadIdx.x;
    if (i < BB * 40) out[i] = val;
}

// ---------------- squared norms ----------------
__global__ void xx_kernel(const float* __restrict__ H, const float* __restrict__ X,
                          float* __restrict__ xx, int cin, int off_in, int use_x)
{
    const int p = blockIdx.x * blockDim.x + threadIdx.x;
    if (p >= BB * NPTS) return;
    float s = 0.f;
    if (use_x) {
        const int b = p >> 10, n = p & 1023;
        for (int c = 0; c < 3; ++c) { const float v = XV(X, b, n, c); s += v * v; }
    } else {
        const float4* r4 = (const float4*)(H + (size_t)p * HC + off_in);
        for (int c4 = 0; c4 < cin / 4; ++c4) {
            const float4 v = r4[c4];
            s += v.x*v.x + v.y*v.y + v.z*v.z + v.w*v.w;
        }
    }
    xx[p] = s;
}

// ---------------- knn (round-11 verified) ----------------
template<int CIN, bool USEX>
__global__ __launch_bounds__(256) void knn_kernel(
    const float* __restrict__ H, const float* __restrict__ X, const float* __restrict__ xx,
    int* __restrict__ idxo, int off_in)
{
    __shared__ __align__(16) float qv[CIN < 4 ? 4 : CIN];
    __shared__ float dist[NPTS];
    const int blk = blockIdx.x;
    const int b = blk >> 10, q = blk & 1023;
    const int tid = threadIdx.x;
    const int base = b * NPTS;

    if (USEX) {
        if (tid < 3) qv[tid] = XV(X, b, q, tid);
    } else {
        for (int c = tid; c < CIN; c += 256) qv[c] = H[(size_t)(base + q) * HC + off_in + c];
    }
    __syncthreads();
    const float xxq = xx[base + q];

    if (USEX) {
        for (int j = 0; j < 4; ++j) {
            const int m = tid + 256 * j;
            const float acc = qv[0]*XV(X,b,m,0) + qv[1]*XV(X,b,m,1) + qv[2]*XV(X,b,m,2);
            dist[m] = (2.f * acc - xxq) - xx[base + m];
        }
    } else {
        const int g = tid >> 3, l = tid & 7;
        for (int it = 0; it < 32; ++it) {
            const int m = g + 32 * it;
            const float4* rm4 = (const float4*)(H + (size_t)(base + m) * HC + off_in);
            float acc = 0.f;
#pragma unroll
            for (int r = 0; r < CIN / 32; ++r) {
                const int c4 = l + 8 * r;
                const float4 v = rm4[c4];
                const float4 a = *(const float4*)&qv[4 * c4];
                acc += a.x*v.x + a.y*v.y + a.z*v.z + a.w*v.w;
            }
            acc += __shfl_xor(acc, 1, 64);
            acc += __shfl_xor(acc, 2, 64);
            acc += __shfl_xor(acc, 4, 64);
            if (l == 0) dist[m] = (2.f * acc - xxq) - xx[base + m];
        }
    }
    __syncthreads();

    if (tid < 64) {
        const int lane = tid;
        unsigned long long key[16];
#pragma unroll
        for (int j = 0; j < 16; ++j) {
            const int m = lane + 64 * j;
            key[j] = dist2key(dist[m], m);
        }
        wave_topk_write(key, idxo, (size_t)(base + q) * KNB, lane);
    }
}

// scalar weight fetch for gemm_conv staging: row og of [W1; W2-W1], column c
__device__ __forceinline__ float wfetch1(const float* __restrict__ W, int og,
                                         int CIN, int COUT, int c)
{
    if (og < COUT) return W[(size_t)og * 2 * CIN + c];
    const float* r0 = W + (size_t)(og - COUT) * 2 * CIN;
    return r0[CIN + c] - r0[c];
}

// ---------------- P GEMM: 64 rows x 128 cols, wl LDS-staged, 2 outs x 16 rows/thread ----------------
__global__ __launch_bounds__(256, 4) void gemm_conv_kernel(
    const float* __restrict__ H, const float* __restrict__ W, float* __restrict__ P,
    int off_in, int CIN, int COUT, int NO128)
{
    __shared__ float hl[32][68];      // [c][n] 64 rows
    __shared__ float wl[32][132];     // [c][og] 128 cols
    const int mblk = blockIdx.x / NO128;
    const int oblk = blockIdx.x - mblk * NO128;
    const int tid = threadIdx.x;
    const int o = tid & 63, grp = tid >> 6;   // grp owns rows [grp*16, grp*16+16)
    const int NO = NO128 * 128;
    const int n0 = mblk * 64;
    const int og0 = oblk * 128 + o;
    const int og1 = og0 + 64;

    float acc0[16], acc1[16];
#pragma unroll
    for (int i = 0; i < 16; ++i) { acc0[i] = 0.f; acc1[i] = 0.f; }

    for (int ct = 0; ct < CIN / 32; ++ct) {
        for (int r = 0; r < 2; ++r) {
            const int e = tid + 256 * r;           // 512 float4s
            const int n = e & 63, c4 = e >> 6;
            const float4 hv = *(const float4*)(H + (size_t)(n0 + n) * HC + off_in + ct * 32 + c4 * 4);
            hl[c4*4+0][n] = hv.x; hl[c4*4+1][n] = hv.y; hl[c4*4+2][n] = hv.z; hl[c4*4+3][n] = hv.w;
        }
        for (int r = 0; r < 16; ++r) {
            const int e = tid + 256 * r;           // 4096 scalars
            const int c_ = e & 31, o_ = e >> 5;
            wl[c_][o_] = wfetch1(W, oblk * 128 + o_, CIN, COUT, ct * 32 + c_);
        }
        __syncthreads();
        for (int c = 0; c < 32; ++c) {
            const float wva = wl[c][o];
            const float wvb = wl[c][o + 64];
            const float* hr = &hl[c][grp * 16];
#pragma unroll
            for (int nn = 0; nn < 4; ++nn) {
                const float4 hv = *(const float4*)(hr + 4 * nn);
                acc0[4*nn+0] += wva * hv.x; acc0[4*nn+1] += wva * hv.y;
                acc0[4*nn+2] += wva * hv.z; acc0[4*nn+3] += wva * hv.w;
                acc1[4*nn+0] += wvb * hv.x; acc1[4*nn+1] += wvb * hv.y;
                acc1[4*nn+2] += wvb * hv.z; acc1[4*nn+3] += wvb * hv.w;
            }
        }
        __syncthreads();
    }

#pragma unroll
    for (int i = 0; i < 16; ++i) {
        P[(size_t)(n0 + grp * 16 + i) * NO + og0] = acc0[i];
        P[(size_t)(n0 + grp * 16 + i) * NO + og1] = acc1[i];
    }
}

// epilogue: y[q,k] = P1[nb] + P2[q]; BN+lrelu+max over k
template<int COUT>
__global__ __launch_bounds__(COUT) void edge_epi_kernel(
    const float* __restrict__ P, const int* __restrict__ idx,
    const float* __restrict__ Bs, const float* __restrict__ G, const float* __restrict__ Be,
    const float* __restrict__ Bm, const float* __restrict__ Bv,
    float* __restrict__ Hout, int off_out)
{
    constexpr int NO = 2 * COUT;
    const int blk = blockIdx.x;
    const int base = (blk >> 10) << 10;
    const int o = threadIdx.x;
    const float s = G[o] / sqrtf(Bv[o] + 1e-5f);
    const float beo = Be[o];
    const float cb = P[(size_t)blk * NO + COUT + o] + Bs[o] - Bm[o];
    float mx = -INFINITY;
    for (int k = 0; k < KNB; ++k) {
        const int m = idx[(size_t)blk * KNB + k];
        const float v = P[(size_t)(base + m) * NO + o];
        float t = (v + cb) * s + beo;
        t = t > 0.f ? t : 0.2f * t;
        mx = fmaxf(mx, t);
    }
    Hout[(size_t)blk * HC + off_out + o] = mx;
}

// ---------------- layer-0 conv (small, round-11 style) ----------------
template<int CIN, int COUT, int OPO, bool USEX>
__global__ __launch_bounds__(COUT / OPO) void conv_kernel(
    const float* __restrict__ H, const float* __restrict__ X, const int* __restrict__ idx,
    const float* __restrict__ W, const float* __restrict__ Bs, const float* __restrict__ G,
    const float* __restrict__ Be, const float* __restrict__ Bm, const float* __restrict__ Bv,
    float* __restrict__ Hout, int off_in, int off_out)
{
    constexpr int TPB = COUT / OPO;
    __shared__ __align__(16) float ctr[CIN];
    __shared__ __align__(16) float nb[KNB][CIN];
    __shared__ int sidx[KNB];
    const int blk = blockIdx.x;
    const int b = blk >> 10, q = blk & 1023;
    const int tid = threadIdx.x;
    const int base = b * NPTS;

    if (tid < KNB) sidx[tid] = idx[(size_t)(base + q) * KNB + tid];
    for (int c = tid; c < CIN; c += TPB)
        ctr[c] = USEX ? XV(X, b, q, c) : H[(size_t)(base + q) * HC + off_in + c];
    __syncthreads();
    for (int t = tid; t < KNB * CIN; t += TPB) {
        const int k = t / CIN, c = t - k * CIN;
        nb[k][c] = USEX ? XV(X, b, sidx[k], c) : H[(size_t)(base + sidx[k]) * HC + off_in + c];
    }
    __syncthreads();

    float acc[KNB];
    float cacc = 0.f;
#pragma unroll
    for (int k = 0; k < KNB; ++k) acc[k] = 0.f;

    const float* wr = W + (size_t)tid * 2 * CIN;
    for (int c = 0; c < CIN; ++c) {
        const float w1 = wr[c], w2 = wr[CIN + c];
        cacc += (w2 - w1) * ctr[c];
#pragma unroll
        for (int k = 0; k < KNB; ++k) acc[k] += w1 * nb[k][c];
    }

    const int o = tid;
    const float s = G[o] / sqrtf(Bv[o] + 1e-5f);
    const float beo = Be[o];
    const float cb = cacc + Bs[o] - Bm[o];
    float mx = -INFINITY;
#pragma unroll
    for (int k = 0; k < KNB; ++k) {
        float t = (acc[k] + cb) * s + beo;
        t = t > 0.f ? t : 0.2f * t;
        mx = fmaxf(mx, t);
    }
    Hout[(size_t)(base + q) * HC + off_out + o] = mx;
}

// ---------------- lc conv + pool: 64n x 128o, wl LDS-staged, 2 outs x 16 rows/thread ----------------
__global__ __launch_bounds__(256, 4) void lcpool_kernel(
    const float* __restrict__ H, const float* __restrict__ W, const float* __restrict__ Bs,
    const float* __restrict__ G, const float* __restrict__ Be,
    const float* __restrict__ Bm, const float* __restrict__ Bv,
    float* __restrict__ pmax, float* __restrict__ psum)
{
    __shared__ float hl[32][68];
    __shared__ float wl[32][132];
    __shared__ float redm[4][128];
    __shared__ float reds[4][128];
    const int bid = blockIdx.x;            // BB * 8 * 16
    const int b = bid >> 7;
    const int rem = bid & 127;
    const int oblk = rem >> 4;             // 0..7  (128 o each)
    const int nblk = rem & 15;             // 0..15 (64 n each)
    const int tid = threadIdx.x;
    const int o = tid & 63;
    const int grp = tid >> 6;
    const int og0 = oblk * 128 + o;
    const int og1 = og0 + 64;
    const int n0 = nblk * 64;
    const size_t hbase = (size_t)b * NPTS * HC;

    float acc0[16], acc1[16];
#pragma unroll
    for (int i = 0; i < 16; ++i) { acc0[i] = 0.f; acc1[i] = 0.f; }

    for (int ct = 0; ct < 16; ++ct) {
        for (int r = 0; r < 2; ++r) {
            const int e = tid + 256 * r;
            const int n = e & 63, c4 = e >> 6;
            const float4 hv = *(const float4*)(H + hbase + (size_t)(n0 + n) * HC + ct * 32 + c4 * 4);
            hl[c4*4+0][n] = hv.x; hl[c4*4+1][n] = hv.y; hl[c4*4+2][n] = hv.z; hl[c4*4+3][n] = hv.w;
        }
        for (int r = 0; r < 16; ++r) {
            const int e = tid + 256 * r;
            const int c_ = e & 31, o_ = e >> 5;
            wl[c_][o_] = W[(size_t)(oblk * 128 + o_) * HC + ct * 32 + c_];
        }
        __syncthreads();
        for (int c = 0; c < 32; ++c) {
            const float wva = wl[c][o];
            const float wvb = wl[c][o + 64];
            const float* hr = &hl[c][grp * 16];
#pragma unroll
            for (int nn = 0; nn < 4; ++nn) {
                const float4 hv = *(const float4*)(hr + 4 * nn);
                acc0[4*nn+0] += wva * hv.x; acc0[4*nn+1] += wva * hv.y;
                acc0[4*nn+2] += wva * hv.z; acc0[4*nn+3] += wva * hv.w;
                acc1[4*nn+0] += wvb * hv.x; acc1[4*nn+1] += wvb * hv.y;
                acc1[4*nn+2] += wvb * hv.z; acc1[4*nn+3] += wvb * hv.w;
            }
        }
        __syncthreads();
    }

#pragma unroll
    for (int p = 0; p < 2; ++p) {
        const int og = p ? og1 : og0;
        const float* acc = p ? acc1 : acc0;
        const float s = G[og] / sqrtf(Bv[og] + 1e-5f);
        const float beo = Be[og];
        const float mb = Bs[og] - Bm[og];
        float pm = -INFINITY, ps = 0.f;
#pragma unroll
        for (int i = 0; i < 16; ++i) {
            float t = (acc[i] + mb) * s + beo;
            t = t > 0.f ? t : 0.2f * t;
            pm = fmaxf(pm, t); ps += t;
        }
        redm[grp][o + 64 * p] = pm; reds[grp][o + 64 * p] = ps;
    }
    __syncthreads();
    if (grp == 0) {
#pragma unroll
        for (int p = 0; p < 2; ++p) {
            const int oo = o + 64 * p;
            float m0 = redm[0][oo], s0 = reds[0][oo];
            for (int i2 = 1; i2 < 4; ++i2) { m0 = fmaxf(m0, redm[i2][oo]); s0 += reds[i2][oo]; }
            pmax[((size_t)b * 16 + nblk) * 1024 + oblk * 128 + oo] = m0;
            psum[((size_t)b * 16 + nblk) * 1024 + oblk * 128 + oo] = s0;
        }
    }
}

__global__ void pool_reduce_kernel(const float* __restrict__ pmax, const float* __restrict__ psum,
                                   float* __restrict__ h2)
{
    const int i = blockIdx.x * 256 + threadIdx.x;
    if (i >= BB * 1024) return;
    const int b = i >> 10, o = i & 1023;
    float mx = -INFINITY, sm = 0.f;
    for (int c = 0; c < 16; ++c) {
        mx = fmaxf(mx, pmax[((size_t)b * 16 + c) * 1024 + o]);
        sm += psum[((size_t)b * 16 + c) * 1024 + o];
    }
    h2[(size_t)b * 2048 + o] = mx;
    h2[(size_t)b * 2048 + 1024 + o] = sm * (1.f / 1024.f);
}

// ---------------- FC head ----------------
__global__ void l0_kernel(const float* __restrict__ h2, const float* __restrict__ W,
                          const float* __restrict__ G, const float* __restrict__ Be,
                          const float* __restrict__ Bm, const float* __restrict__ Bv,
                          float* __restrict__ h3)
{
    const int i = blockIdx.x * 256 + threadIdx.x;
    if (i >= BB * 512) return;
    const int b = i >> 9, o = i & 511;
    const float4* w4 = (const float4*)(W + (size_t)o * 2048);
    const float4* h4p = (const float4*)(h2 + (size_t)b * 2048);
    float acc = 0.f;
    for (int c = 0; c < 512; ++c) {
        const float4 wv = w4[c]; const float4 hv = h4p[c];
        acc += wv.x*hv.x + wv.y*hv.y + wv.z*hv.z + wv.w*hv.w;
    }
    const float s = G[o] / sqrtf(Bv[o] + 1e-5f);
    float t = (acc - Bm[o]) * s + Be[o];
    t = t > 0.f ? t : 0.2f * t;
    h3[(size_t)b * 512 + o] = t;
}

__global__ void l1_kernel(const float* __restrict__ h3, const float* __restrict__ W,
                          const float* __restrict__ Bs, const float* __restrict__ G,
                          const float* __restrict__ Be, const float* __restrict__ Bm,
                          const float* __restrict__ Bv, float* __restrict__ h4o)
{
    const int i = blockIdx.x * 256 + threadIdx.x;
    if (i >= BB * 256) return;
    const int b = i >> 8, o = i & 255;
    const float4* w4 = (const float4*)(W + (size_t)o * 512);
    const float4* hv4 = (const float4*)(h3 + (size_t)b * 512);
    float acc = 0.f;
    for (int c = 0; c < 128; ++c) {
        const float4 wv = w4[c]; const float4 hv = hv4[c];
        acc += wv.x*hv.x + wv.y*hv.y + wv.z*hv.z + wv.w*hv.w;
    }
    acc += Bs[o];
    const float s = G[o] / sqrtf(Bv[o] + 1e-5f);
    float t = (acc - Bm[o]) * s + Be[o];
    t = t > 0.f ? t : 0.2f * t;
    h4o[(size_t)b * 256 + o] = t;
}

__global__ void out_kernel(const float* __restrict__ h4, const float* __restrict__ W,
                           const float* __restrict__ Bs, float* __restrict__ out)
{
    const int i = blockIdx.x * 256 + threadIdx.x;
    if (i >= BB * 40) return;
    const int b = i / 40, o = i % 40;
    const float4* w4 = (const float4*)(W + (size_t)o * 256);
    const float4* hv4 = (const float4*)(h4 + (size_t)b * 256);
    float acc = 0.f;
    for (int c = 0; c < 64; ++c) {
        const float4 wv = w4[c]; const float4 hv = hv4[c];
        acc += wv.x*hv.x + wv.y*hv.y + wv.z*hv.z + wv.w*hv.w;
    }
    acc += Bs[o];
    out[(size_t)b * 40 + o] = acc;
}

extern "C" void kernel_launch(void* const* d_in, const int* in_sizes, int n_in,
                              void* d_out, int out_size, void* d_ws, size_t ws_size,
                              hipStream_t stream)
{
    static const int expect[44] = {
        49152, 384,64,64,64,64,64, 8192,64,64,64,64,64, 16384,128,128,128,128,128,
        65536,256,256,256,256,256, 524288,1024,1024,1024,1024,1024,
        1048576,512,512,512,512, 131072,256,256,256,256,256, 10240,40};
    int bad = -1;
    if (n_in != 44) bad = 100;
    else if (out_size != BB * 40) bad = 101;
    else {
        for (int i = 0; i < 44; ++i) if (in_sizes[i] != expect[i]) { bad = i; break; }
    }
    if (bad >= 0) {
        sentinel_kernel<<<3, 256, 0, stream>>>((float*)d_out, 500.f + (float)bad);
        return;
    }

    const float* X = (const float*)d_in[0];
    const float *CW[4], *CB[4], *CG[4], *CBE[4], *CM[4], *CV[4];
    for (int i = 0; i < 4; ++i) {
        CW[i]  = (const float*)d_in[1 + 6*i]; CB[i] = (const float*)d_in[2 + 6*i];
        CG[i]  = (const float*)d_in[3 + 6*i]; CBE[i] = (const float*)d_in[4 + 6*i];
        CM[i]  = (const float*)d_in[5 + 6*i]; CV[i] = (const float*)d_in[6 + 6*i];
    }
    const float* LCW = (const float*)d_in[25]; const float* LCB = (const float*)d_in[26];
    const float* LCG = (const float*)d_in[27]; const float* LCBE = (const float*)d_in[28];
    const float* LCM = (const float*)d_in[29]; const float* LCV = (const float*)d_in[30];
    const float* L0W = (const float*)d_in[31]; const float* L0G = (const float*)d_in[32];
    const float* L0BE = (const float*)d_in[33]; const float* L0M = (const float*)d_in[34];
    const float* L0V = (const float*)d_in[35];
    const float* L1W = (const float*)d_in[36]; const float* L1B = (const float*)d_in[37];
    const float* L1G = (const float*)d_in[38]; const float* L1BE = (const float*)d_in[39];
    const float* L1M = (const float*)d_in[40]; const float* L1V = (const float*)d_in[41];
    const float* OW = (const float*)d_in[42]; const float* OB = (const float*)d_in[43];

    float* H    = (float*)d_ws;
    float* XX   = H + (size_t)BB * NPTS * HC;
    int*   IDX  = (int*)(XX + BB * NPTS);
    float* P    = (float*)(IDX + (size_t)BB * NPTS * KNB);
    float* PMAX = P + (size_t)BB * NPTS * 512;
    float* PSUM = PMAX + BB * 16 * 1024;
    float* H2   = PSUM + BB * 16 * 1024;
    float* H3   = H2 + BB * 2048;
    float* H4   = H3 + BB * 512;
    const size_t need_bytes = (size_t)((H4 + BB * 256) - H) * 4;
    const bool use_P = (ws_size >= need_bytes);

    float* fPMAX = P;
    float* fPSUM = fPMAX + BB * 16 * 1024;
    float* fH2   = fPSUM + BB * 16 * 1024;
    float* fH3   = fH2 + BB * 2048;
    float* fH4   = fH3 + BB * 512;

    const int M = BB * NPTS;

    // ---- layer 0 ----
    xx_kernel<<<M/256, 256, 0, stream>>>(H, X, XX, 3, 0, 1);
    knn_kernel<3,true><<<M, 256, 0, stream>>>(H, X, XX, IDX, 0);
    conv_kernel<3,64,1,true><<<M, 64, 0, stream>>>(H, X, IDX,
        CW[0], CB[0], CG[0], CBE[0], CM[0], CV[0], H, 0, 0);

    if (use_P) {
        // ---- layer 1 ----
        xx_kernel<<<M/256, 256, 0, stream>>>(H, X, XX, 64, 0, 0);
        knn_kernel<64,false><<<M, 256, 0, stream>>>(H, X, XX, IDX, 0);
        gemm_conv_kernel<<<(M/64)*1, 256, 0, stream>>>(H, CW[1], P, 0, 64, 64, 1);
        edge_epi_kernel<64><<<M, 64, 0, stream>>>(P, IDX,
            CB[1], CG[1], CBE[1], CM[1], CV[1], H, 64);

        // ---- layer 2 ----
        xx_kernel<<<M/256, 256, 0, stream>>>(H, X, XX, 64, 64, 0);
        knn_kernel<64,false><<<M, 256, 0, stream>>>(H, X, XX, IDX, 64);
        gemm_conv_kernel<<<(M/64)*2, 256, 0, stream>>>(H, CW[2], P, 64, 64, 128, 2);
        edge_epi_kernel<128><<<M, 128, 0, stream>>>(P, IDX,
            CB[2], CG[2], CBE[2], CM[2], CV[2], H, 128);

        // ---- layer 3 ----
        xx_kernel<<<M/256, 256, 0, stream>>>(H, X, XX, 128, 128, 0);
        knn_kernel<128,false><<<M, 256, 0, stream>>>(H, X, XX, IDX, 128);
        gemm_conv_kernel<<<(M/64)*4, 256, 0, stream>>>(H, CW[3], P, 128, 128, 256, 4);
        edge_epi_kernel<256><<<M, 256, 0, stream>>>(P, IDX,
            CB[3], CG[3], CBE[3], CM[3], CV[3], H, 256);

        lcpool_kernel<<<BB*8*16, 256, 0, stream>>>(H, LCW, LCB, LCG, LCBE, LCM, LCV, PMAX, PSUM);
        pool_reduce_kernel<<<BB*1024/256, 256, 0, stream>>>(PMAX, PSUM, H2);
        l0_kernel<<<(BB*512+255)/256, 256, 0, stream>>>(H2, L0W, L0G, L0BE, L0M, L0V, H3);
        l1_kernel<<<(BB*256+255)/256, 256, 0, stream>>>(H3, L1W, L1B, L1G, L1BE, L1M, L1V, H4);
        out_kernel<<<(BB*40+255)/256, 256, 0, stream>>>(H4, OW, OB, (float*)d_out);
    } else {
        xx_kernel<<<M/256, 256, 0, stream>>>(H, X, XX, 64, 0, 0);
        knn_kernel<64,false><<<M, 256, 0, stream>>>(H, X, XX, IDX, 0);
        conv_kernel<64,64,1,false><<<M, 64, 0, stream>>>(H, X, IDX,
            CW[1], CB[1], CG[1], CBE[1], CM[1], CV[1], H, 0, 64);

        xx_kernel<<<M/256, 256, 0, stream>>>(H, X, XX, 64, 64, 0);
        knn_kernel<64,false><<<M, 256, 0, stream>>>(H, X, XX, IDX, 64);
        conv_kernel<64,128,1,false><<<M, 128, 0, stream>>>(H, X, IDX,
            CW[2], CB[2], CG[2], CBE[2], CM[2], CV[2], H, 64, 128);

        xx_kernel<<<M/256, 256, 0, stream>>>(H, X, XX, 128, 128, 0);
        knn_kernel<128,false><<<M, 256, 0, stream>>>(H, X, XX, IDX, 128);
        conv_kernel<128,256,1,false><<<M, 256, 0, stream>>>(H, X, IDX,
            CW[3], CB[3], CG[3], CBE[3], CM[3], CV[3], H, 128, 256);

        lcpool_kernel<<<BB*8*16, 256, 0, stream>>>(H, LCW, LCB, LCG, LCBE, LCM, LCV, fPMAX, fPSUM);
        pool_reduce_kernel<<<BB*1024/256, 256, 0, stream>>>(fPMAX, fPSUM, fH2);
        l0_kernel<<<(BB*512+255)/256, 256, 0, stream>>>(fH2, L0W, L0G, L0BE, L0M, L0V, fH3);
        l1_kernel<<<(BB*256+255)/256, 256, 0, stream>>>(fH3, L1W, L1B, L1G, L1BE, L1M, L1V, fH4);
        out_kernel<<<(BB*40+255)/256, 256, 0, stream>>>(fH4, OW, OB, (float*)d_out);
    }
}

// Round 16
// 1247.538 us; speedup vs baseline: 2.2787x; 1.3185x over previous
//
#include <hip/hip_runtime.h>
#include <hip/hip_bf16.h>

#define BB 16
#define NPTS 1024
#define KNB 20
#define HC 512

__device__ __forceinline__ float XV(const float* __restrict__ X, int b, int n, int c)
{
    return X[((size_t)b * NPTS + n) * 3 + c];
}

__device__ __forceinline__ unsigned long long dist2key(float d, int m)
{
    unsigned u = __float_as_uint(d);
    u = (u & 0x80000000u) ? ~u : (u | 0x80000000u);
    return ((unsigned long long)u << 32) | (unsigned)(1023 - m);
}

__device__ __forceinline__ void wave_topk_write(unsigned long long* key,
                                                int* __restrict__ idxo,
                                                size_t obase, int lane)
{
    for (int it = 0; it < KNB; ++it) {
        unsigned long long best = 0ull; int bj = -1;
#pragma unroll
        for (int j = 0; j < 16; ++j) if (key[j] > best) { best = key[j]; bj = j; }
        unsigned long long wbest = best;
        for (int off = 32; off > 0; off >>= 1) {
            const unsigned long long o = __shfl_down(wbest, off, 64);
            if (o > wbest) wbest = o;
        }
        wbest = __shfl(wbest, 0, 64);
        if (best == wbest && bj >= 0) key[bj] = 0ull;
        if (lane == 0) idxo[obase + it] = 1023 - (int)(wbest & 0xFFFFFFFFull);
    }
}

__global__ void sentinel_kernel(float* __restrict__ out, float val)
{
    const int i = blockIdx.x * 256 + threadIdx.x;
    if (i < BB * 40) out[i] = val;
}

// ---------------- squared norms ----------------
__global__ void xx_kernel(const float* __restrict__ H, const float* __restrict__ X,
                          float* __restrict__ xx, int cin, int off_in, int use_x)
{
    const int p = blockIdx.x * blockDim.x + threadIdx.x;
    if (p >= BB * NPTS) return;
    float s = 0.f;
    if (use_x) {
        const int b = p >> 10, n = p & 1023;
        for (int c = 0; c < 3; ++c) { const float v = XV(X, b, n, c); s += v * v; }
    } else {
        const float4* r4 = (const float4*)(H + (size_t)p * HC + off_in);
        for (int c4 = 0; c4 < cin / 4; ++c4) {
            const float4 v = r4[c4];
            s += v.x*v.x + v.y*v.y + v.z*v.z + v.w*v.w;
        }
    }
    xx[p] = s;
}

// ---------------- knn, 4 queries per block ----------------
// dist phase: 8-lane groups load each candidate row ONCE, dot vs 4 register-
// resident query chunks (traffic /4). Selection: 4 waves in parallel, one per
// query, verified wave_topk_write.
template<int CIN>
__global__ __launch_bounds__(256, 3) void knn4_kernel(
    const float* __restrict__ H, const float* __restrict__ xx,
    int* __restrict__ idxo, int off_in)
{
    __shared__ __align__(16) float qv[4][CIN];
    __shared__ float dist[4][NPTS];
    __shared__ float sxxq[4];
    const int blk = blockIdx.x;              // M/4 blocks
    const int q0g = blk * 4;
    const int b = q0g >> 10, q0 = q0g & 1023;
    const int tid = threadIdx.x;
    const int base = b * NPTS;

    for (int t = tid; t < 4 * CIN; t += 256) {
        const int q = t / CIN, c = t - q * CIN;
        qv[q][c] = H[(size_t)(base + q0 + q) * HC + off_in + c];
    }
    if (tid < 4) sxxq[tid] = xx[base + q0 + tid];
    __syncthreads();

    const int g = tid >> 3, l = tid & 7;     // 32 groups of 8
    float4 aq[4][CIN / 32];
#pragma unroll
    for (int q = 0; q < 4; ++q)
#pragma unroll
        for (int r = 0; r < CIN / 32; ++r)
            aq[q][r] = *(const float4*)&qv[q][4 * (l + 8 * r)];

    for (int it = 0; it < 32; ++it) {
        const int m = g + 32 * it;
        float acc[4] = {0.f, 0.f, 0.f, 0.f};
#pragma unroll
        for (int r = 0; r < CIN / 32; ++r) {
            const float4 v = *(const float4*)(H + (size_t)(base + m) * HC + off_in + 4 * (l + 8 * r));
#pragma unroll
            for (int q = 0; q < 4; ++q)
                acc[q] += aq[q][r].x*v.x + aq[q][r].y*v.y + aq[q][r].z*v.z + aq[q][r].w*v.w;
        }
#pragma unroll
        for (int q = 0; q < 4; ++q) {
            acc[q] += __shfl_xor(acc[q], 1, 64);
            acc[q] += __shfl_xor(acc[q], 2, 64);
            acc[q] += __shfl_xor(acc[q], 4, 64);
        }
        if (l == 0) {
            const float xxm = xx[base + m];
#pragma unroll
            for (int q = 0; q < 4; ++q)
                dist[q][m] = (2.f * acc[q] - sxxq[q]) - xxm;
        }
    }
    __syncthreads();

    const int w = tid >> 6, lane = tid & 63;
    unsigned long long key[16];
#pragma unroll
    for (int j = 0; j < 16; ++j) {
        const int m = lane + 64 * j;
        key[j] = dist2key(dist[w][m], m);
    }
    wave_topk_write(key, idxo, (size_t)(base + q0 + w) * KNB, lane);
}

// knn over x (cin=3), 4 queries per block
__global__ __launch_bounds__(256, 3) void knn4x_kernel(
    const float* __restrict__ X, const float* __restrict__ xx, int* __restrict__ idxo)
{
    __shared__ float qv[4][4];
    __shared__ float dist[4][NPTS];
    __shared__ float sxxq[4];
    const int blk = blockIdx.x;
    const int q0g = blk * 4;
    const int b = q0g >> 10, q0 = q0g & 1023;
    const int tid = threadIdx.x;
    const int base = b * NPTS;

    if (tid < 4) {
        for (int c = 0; c < 3; ++c) qv[tid][c] = XV(X, b, q0 + tid, c);
        sxxq[tid] = xx[base + q0 + tid];
    }
    __syncthreads();

    for (int j = 0; j < 4; ++j) {
        const int m = tid + 256 * j;
        const float r0 = XV(X, b, m, 0), r1 = XV(X, b, m, 1), r2 = XV(X, b, m, 2);
        const float xxm = xx[base + m];
#pragma unroll
        for (int q = 0; q < 4; ++q) {
            const float acc = qv[q][0]*r0 + qv[q][1]*r1 + qv[q][2]*r2;
            dist[q][m] = (2.f * acc - sxxq[q]) - xxm;
        }
    }
    __syncthreads();

    const int w = tid >> 6, lane = tid & 63;
    unsigned long long key[16];
#pragma unroll
    for (int j = 0; j < 16; ++j) {
        const int m = lane + 64 * j;
        key[j] = dist2key(dist[w][m], m);
    }
    wave_topk_write(key, idxo, (size_t)(base + q0 + w) * KNB, lane);
}

// scalar weight fetch for gemm_conv staging: row og of [W1; W2-W1], column c
__device__ __forceinline__ float wfetch1(const float* __restrict__ W, int og,
                                         int CIN, int COUT, int c)
{
    if (og < COUT) return W[(size_t)og * 2 * CIN + c];
    const float* r0 = W + (size_t)(og - COUT) * 2 * CIN;
    return r0[CIN + c] - r0[c];
}

// ---------------- P GEMM: 64 rows x 128 cols, wl LDS-staged, 2 outs x 16 rows/thread ----------------
__global__ __launch_bounds__(256, 4) void gemm_conv_kernel(
    const float* __restrict__ H, const float* __restrict__ W, float* __restrict__ P,
    int off_in, int CIN, int COUT, int NO128)
{
    __shared__ float hl[32][68];
    __shared__ float wl[32][132];
    const int mblk = blockIdx.x / NO128;
    const int oblk = blockIdx.x - mblk * NO128;
    const int tid = threadIdx.x;
    const int o = tid & 63, grp = tid >> 6;
    const int NO = NO128 * 128;
    const int n0 = mblk * 64;
    const int og0 = oblk * 128 + o;
    const int og1 = og0 + 64;

    float acc0[16], acc1[16];
#pragma unroll
    for (int i = 0; i < 16; ++i) { acc0[i] = 0.f; acc1[i] = 0.f; }

    for (int ct = 0; ct < CIN / 32; ++ct) {
        for (int r = 0; r < 2; ++r) {
            const int e = tid + 256 * r;
            const int n = e & 63, c4 = e >> 6;
            const float4 hv = *(const float4*)(H + (size_t)(n0 + n) * HC + off_in + ct * 32 + c4 * 4);
            hl[c4*4+0][n] = hv.x; hl[c4*4+1][n] = hv.y; hl[c4*4+2][n] = hv.z; hl[c4*4+3][n] = hv.w;
        }
        for (int r = 0; r < 16; ++r) {
            const int e = tid + 256 * r;
            const int c_ = e & 31, o_ = e >> 5;
            wl[c_][o_] = wfetch1(W, oblk * 128 + o_, CIN, COUT, ct * 32 + c_);
        }
        __syncthreads();
        for (int c = 0; c < 32; ++c) {
            const float wva = wl[c][o];
            const float wvb = wl[c][o + 64];
            const float* hr = &hl[c][grp * 16];
#pragma unroll
            for (int nn = 0; nn < 4; ++nn) {
                const float4 hv = *(const float4*)(hr + 4 * nn);
                acc0[4*nn+0] += wva * hv.x; acc0[4*nn+1] += wva * hv.y;
                acc0[4*nn+2] += wva * hv.z; acc0[4*nn+3] += wva * hv.w;
                acc1[4*nn+0] += wvb * hv.x; acc1[4*nn+1] += wvb * hv.y;
                acc1[4*nn+2] += wvb * hv.z; acc1[4*nn+3] += wvb * hv.w;
            }
        }
        __syncthreads();
    }

#pragma unroll
    for (int i = 0; i < 16; ++i) {
        P[(size_t)(n0 + grp * 16 + i) * NO + og0] = acc0[i];
        P[(size_t)(n0 + grp * 16 + i) * NO + og1] = acc1[i];
    }
}

// epilogue: y[q,k] = P1[nb] + P2[q]; BN+lrelu+max over k
template<int COUT>
__global__ __launch_bounds__(COUT) void edge_epi_kernel(
    const float* __restrict__ P, const int* __restrict__ idx,
    const float* __restrict__ Bs, const float* __restrict__ G, const float* __restrict__ Be,
    const float* __restrict__ Bm, const float* __restrict__ Bv,
    float* __restrict__ Hout, int off_out)
{
    constexpr int NO = 2 * COUT;
    const int blk = blockIdx.x;
    const int base = (blk >> 10) << 10;
    const int o = threadIdx.x;
    const float s = G[o] / sqrtf(Bv[o] + 1e-5f);
    const float beo = Be[o];
    const float cb = P[(size_t)blk * NO + COUT + o] + Bs[o] - Bm[o];
    float mx = -INFINITY;
    for (int k = 0; k < KNB; ++k) {
        const int m = idx[(size_t)blk * KNB + k];
        const float v = P[(size_t)(base + m) * NO + o];
        float t = (v + cb) * s + beo;
        t = t > 0.f ? t : 0.2f * t;
        mx = fmaxf(mx, t);
    }
    Hout[(size_t)blk * HC + off_out + o] = mx;
}

// ---------------- layer-0 conv ----------------
template<int CIN, int COUT, bool USEX>
__global__ __launch_bounds__(COUT) void conv_kernel(
    const float* __restrict__ H, const float* __restrict__ X, const int* __restrict__ idx,
    const float* __restrict__ W, const float* __restrict__ Bs, const float* __restrict__ G,
    const float* __restrict__ Be, const float* __restrict__ Bm, const float* __restrict__ Bv,
    float* __restrict__ Hout, int off_in, int off_out)
{
    __shared__ __align__(16) float ctr[CIN];
    __shared__ __align__(16) float nb[KNB][CIN];
    __shared__ int sidx[KNB];
    const int blk = blockIdx.x;
    const int b = blk >> 10, q = blk & 1023;
    const int tid = threadIdx.x;
    const int base = b * NPTS;

    if (tid < KNB) sidx[tid] = idx[(size_t)(base + q) * KNB + tid];
    for (int c = tid; c < CIN; c += COUT)
        ctr[c] = USEX ? XV(X, b, q, c) : H[(size_t)(base + q) * HC + off_in + c];
    __syncthreads();
    for (int t = tid; t < KNB * CIN; t += COUT) {
        const int k = t / CIN, c = t - k * CIN;
        nb[k][c] = USEX ? XV(X, b, sidx[k], c) : H[(size_t)(base + sidx[k]) * HC + off_in + c];
    }
    __syncthreads();

    float acc[KNB];
    float cacc = 0.f;
#pragma unroll
    for (int k = 0; k < KNB; ++k) acc[k] = 0.f;

    const float* wr = W + (size_t)tid * 2 * CIN;
    for (int c = 0; c < CIN; ++c) {
        const float w1 = wr[c], w2 = wr[CIN + c];
        cacc += (w2 - w1) * ctr[c];
#pragma unroll
        for (int k = 0; k < KNB; ++k) acc[k] += w1 * nb[k][c];
    }

    const int o = tid;
    const float s = G[o] / sqrtf(Bv[o] + 1e-5f);
    const float beo = Be[o];
    const float cb = cacc + Bs[o] - Bm[o];
    float mx = -INFINITY;
#pragma unroll
    for (int k = 0; k < KNB; ++k) {
        float t = (acc[k] + cb) * s + beo;
        t = t > 0.f ? t : 0.2f * t;
        mx = fmaxf(mx, t);
    }
    Hout[(size_t)(base + q) * HC + off_out + o] = mx;
}

// ---------------- lc conv + pool: 64n x 128o, wl LDS-staged, 2 outs x 16 rows/thread ----------------
__global__ __launch_bounds__(256, 4) void lcpool_kernel(
    const float* __restrict__ H, const float* __restrict__ W, const float* __restrict__ Bs,
    const float* __restrict__ G, const float* __restrict__ Be,
    const float* __restrict__ Bm, const float* __restrict__ Bv,
    float* __restrict__ pmax, float* __restrict__ psum)
{
    __shared__ float hl[32][68];
    __shared__ float wl[32][132];
    __shared__ float redm[4][128];
    __shared__ float reds[4][128];
    const int bid = blockIdx.x;
    const int b = bid >> 7;
    const int rem = bid & 127;
    const int oblk = rem >> 4;
    const int nblk = rem & 15;
    const int tid = threadIdx.x;
    const int o = tid & 63;
    const int grp = tid >> 6;
    const int og0 = oblk * 128 + o;
    const int og1 = og0 + 64;
    const int n0 = nblk * 64;
    const size_t hbase = (size_t)b * NPTS * HC;

    float acc0[16], acc1[16];
#pragma unroll
    for (int i = 0; i < 16; ++i) { acc0[i] = 0.f; acc1[i] = 0.f; }

    for (int ct = 0; ct < 16; ++ct) {
        for (int r = 0; r < 2; ++r) {
            const int e = tid + 256 * r;
            const int n = e & 63, c4 = e >> 6;
            const float4 hv = *(const float4*)(H + hbase + (size_t)(n0 + n) * HC + ct * 32 + c4 * 4);
            hl[c4*4+0][n] = hv.x; hl[c4*4+1][n] = hv.y; hl[c4*4+2][n] = hv.z; hl[c4*4+3][n] = hv.w;
        }
        for (int r = 0; r < 16; ++r) {
            const int e = tid + 256 * r;
            const int c_ = e & 31, o_ = e >> 5;
            wl[c_][o_] = W[(size_t)(oblk * 128 + o_) * HC + ct * 32 + c_];
        }
        __syncthreads();
        for (int c = 0; c < 32; ++c) {
            const float wva = wl[c][o];
            const float wvb = wl[c][o + 64];
            const float* hr = &hl[c][grp * 16];
#pragma unroll
            for (int nn = 0; nn < 4; ++nn) {
                const float4 hv = *(const float4*)(hr + 4 * nn);
                acc0[4*nn+0] += wva * hv.x; acc0[4*nn+1] += wva * hv.y;
                acc0[4*nn+2] += wva * hv.z; acc0[4*nn+3] += wva * hv.w;
                acc1[4*nn+0] += wvb * hv.x; acc1[4*nn+1] += wvb * hv.y;
                acc1[4*nn+2] += wvb * hv.z; acc1[4*nn+3] += wvb * hv.w;
            }
        }
        __syncthreads();
    }

#pragma unroll
    for (int p = 0; p < 2; ++p) {
        const int og = p ? og1 : og0;
        const float* acc = p ? acc1 : acc0;
        const float s = G[og] / sqrtf(Bv[og] + 1e-5f);
        const float beo = Be[og];
        const float mb = Bs[og] - Bm[og];
        float pm = -INFINITY, ps = 0.f;
#pragma unroll
        for (int i = 0; i < 16; ++i) {
            float t = (acc[i] + mb) * s + beo;
            t = t > 0.f ? t : 0.2f * t;
            pm = fmaxf(pm, t); ps += t;
        }
        redm[grp][o + 64 * p] = pm; reds[grp][o + 64 * p] = ps;
    }
    __syncthreads();
    if (grp == 0) {
#pragma unroll
        for (int p = 0; p < 2; ++p) {
            const int oo = o + 64 * p;
            float m0 = redm[0][oo], s0 = reds[0][oo];
            for (int i2 = 1; i2 < 4; ++i2) { m0 = fmaxf(m0, redm[i2][oo]); s0 += reds[i2][oo]; }
            pmax[((size_t)b * 16 + nblk) * 1024 + oblk * 128 + oo] = m0;
            psum[((size_t)b * 16 + nblk) * 1024 + oblk * 128 + oo] = s0;
        }
    }
}

__global__ void pool_reduce_kernel(const float* __restrict__ pmax, const float* __restrict__ psum,
                                   float* __restrict__ h2)
{
    const int i = blockIdx.x * 256 + threadIdx.x;
    if (i >= BB * 1024) return;
    const int b = i >> 10, o = i & 1023;
    float mx = -INFINITY, sm = 0.f;
    for (int c = 0; c < 16; ++c) {
        mx = fmaxf(mx, pmax[((size_t)b * 16 + c) * 1024 + o]);
        sm += psum[((size_t)b * 16 + c) * 1024 + o];
    }
    h2[(size_t)b * 2048 + o] = mx;
    h2[(size_t)b * 2048 + 1024 + o] = sm * (1.f / 1024.f);
}

// ---------------- FC head ----------------
__global__ void l0_kernel(const float* __restrict__ h2, const float* __restrict__ W,
                          const float* __restrict__ G, const float* __restrict__ Be,
                          const float* __restrict__ Bm, const float* __restrict__ Bv,
                          float* __restrict__ h3)
{
    const int i = blockIdx.x * 256 + threadIdx.x;
    if (i >= BB * 512) return;
    const int b = i >> 9, o = i & 511;
    const float4* w4 = (const float4*)(W + (size_t)o * 2048);
    const float4* h4p = (const float4*)(h2 + (size_t)b * 2048);
    float acc = 0.f;
    for (int c = 0; c < 512; ++c) {
        const float4 wv = w4[c]; const float4 hv = h4p[c];
        acc += wv.x*hv.x + wv.y*hv.y + wv.z*hv.z + wv.w*hv.w;
    }
    const float s = G[o] / sqrtf(Bv[o] + 1e-5f);
    float t = (acc - Bm[o]) * s + Be[o];
    t = t > 0.f ? t : 0.2f * t;
    h3[(size_t)b * 512 + o] = t;
}

__global__ void l1_kernel(const float* __restrict__ h3, const float* __restrict__ W,
                          const float* __restrict__ Bs, const float* __restrict__ G,
                          const float* __restrict__ Be, const float* __restrict__ Bm,
                          const float* __restrict__ Bv, float* __restrict__ h4o)
{
    const int i = blockIdx.x * 256 + threadIdx.x;
    if (i >= BB * 256) return;
    const int b = i >> 8, o = i & 255;
    const float4* w4 = (const float4*)(W + (size_t)o * 512);
    const float4* hv4 = (const float4*)(h3 + (size_t)b * 512);
    float acc = 0.f;
    for (int c = 0; c < 128; ++c) {
        const float4 wv = w4[c]; const float4 hv = hv4[c];
        acc += wv.x*hv.x + wv.y*hv.y + wv.z*hv.z + wv.w*hv.w;
    }
    acc += Bs[o];
    const float s = G[o] / sqrtf(Bv[o] + 1e-5f);
    float t = (acc - Bm[o]) * s + Be[o];
    t = t > 0.f ? t : 0.2f * t;
    h4o[(size_t)b * 256 + o] = t;
}

__global__ void out_kernel(const float* __restrict__ h4, const float* __restrict__ W,
                           const float* __restrict__ Bs, float* __restrict__ out)
{
    const int i = blockIdx.x * 256 + threadIdx.x;
    if (i >= BB * 40) return;
    const int b = i / 40, o = i % 40;
    const float4* w4 = (const float4*)(W + (size_t)o * 256);
    const float4* hv4 = (const float4*)(h4 + (size_t)b * 256);
    float acc = 0.f;
    for (int c = 0; c < 64; ++c) {
        const float4 wv = w4[c]; const float4 hv = hv4[c];
        acc += wv.x*hv.x + wv.y*hv.y + wv.z*hv.z + wv.w*hv.w;
    }
    acc += Bs[o];
    out[(size_t)b * 40 + o] = acc;
}

extern "C" void kernel_launch(void* const* d_in, const int* in_sizes, int n_in,
                              void* d_out, int out_size, void* d_ws, size_t ws_size,
                              hipStream_t stream)
{
    static const int expect[44] = {
        49152, 384,64,64,64,64,64, 8192,64,64,64,64,64, 16384,128,128,128,128,128,
        65536,256,256,256,256,256, 524288,1024,1024,1024,1024,1024,
        1048576,512,512,512,512, 131072,256,256,256,256,256, 10240,40};
    int bad = -1;
    if (n_in != 44) bad = 100;
    else if (out_size != BB * 40) bad = 101;
    else {
        for (int i = 0; i < 44; ++i) if (in_sizes[i] != expect[i]) { bad = i; break; }
    }
    if (bad >= 0) {
        sentinel_kernel<<<3, 256, 0, stream>>>((float*)d_out, 500.f + (float)bad);
        return;
    }

    const float* X = (const float*)d_in[0];
    const float *CW[4], *CB[4], *CG[4], *CBE[4], *CM[4], *CV[4];
    for (int i = 0; i < 4; ++i) {
        CW[i]  = (const float*)d_in[1 + 6*i]; CB[i] = (const float*)d_in[2 + 6*i];
        CG[i]  = (const float*)d_in[3 + 6*i]; CBE[i] = (const float*)d_in[4 + 6*i];
        CM[i]  = (const float*)d_in[5 + 6*i]; CV[i] = (const float*)d_in[6 + 6*i];
    }
    const float* LCW = (const float*)d_in[25]; const float* LCB = (const float*)d_in[26];
    const float* LCG = (const float*)d_in[27]; const float* LCBE = (const float*)d_in[28];
    const float* LCM = (const float*)d_in[29]; const float* LCV = (const float*)d_in[30];
    const float* L0W = (const float*)d_in[31]; const float* L0G = (const float*)d_in[32];
    const float* L0BE = (const float*)d_in[33]; const float* L0M = (const float*)d_in[34];
    const float* L0V = (const float*)d_in[35];
    const float* L1W = (const float*)d_in[36]; const float* L1B = (const float*)d_in[37];
    const float* L1G = (const float*)d_in[38]; const float* L1BE = (const float*)d_in[39];
    const float* L1M = (const float*)d_in[40]; const float* L1V = (const float*)d_in[41];
    const float* OW = (const float*)d_in[42]; const float* OB = (const float*)d_in[43];

    float* H    = (float*)d_ws;
    float* XX   = H + (size_t)BB * NPTS * HC;
    int*   IDX  = (int*)(XX + BB * NPTS);
    float* P    = (float*)(IDX + (size_t)BB * NPTS * KNB);
    float* PMAX = P + (size_t)BB * NPTS * 512;
    float* PSUM = PMAX + BB * 16 * 1024;
    float* H2   = PSUM + BB * 16 * 1024;
    float* H3   = H2 + BB * 2048;
    float* H4   = H3 + BB * 512;
    const size_t need_bytes = (size_t)((H4 + BB * 256) - H) * 4;
    const bool use_P = (ws_size >= need_bytes);

    float* fPMAX = P;
    float* fPSUM = fPMAX + BB * 16 * 1024;
    float* fH2   = fPSUM + BB * 16 * 1024;
    float* fH3   = fH2 + BB * 2048;
    float* fH4   = fH3 + BB * 512;

    const int M = BB * NPTS;

    // ---- layer 0 ----
    xx_kernel<<<M/256, 256, 0, stream>>>(H, X, XX, 3, 0, 1);
    knn4x_kernel<<<M/4, 256, 0, stream>>>(X, XX, IDX);
    conv_kernel<3,64,true><<<M, 64, 0, stream>>>(H, X, IDX,
        CW[0], CB[0], CG[0], CBE[0], CM[0], CV[0], H, 0, 0);

    if (use_P) {
        // ---- layer 1 ----
        xx_kernel<<<M/256, 256, 0, stream>>>(H, X, XX, 64, 0, 0);
        knn4_kernel<64><<<M/4, 256, 0, stream>>>(H, XX, IDX, 0);
        gemm_conv_kernel<<<(M/64)*1, 256, 0, stream>>>(H, CW[1], P, 0, 64, 64, 1);
        edge_epi_kernel<64><<<M, 64, 0, stream>>>(P, IDX,
            CB[1], CG[1], CBE[1], CM[1], CV[1], H, 64);

        // ---- layer 2 ----
        xx_kernel<<<M/256, 256, 0, stream>>>(H, X, XX, 64, 64, 0);
        knn4_kernel<64><<<M/4, 256, 0, stream>>>(H, XX, IDX, 64);
        gemm_conv_kernel<<<(M/64)*2, 256, 0, stream>>>(H, CW[2], P, 64, 64, 128, 2);
        edge_epi_kernel<128><<<M, 128, 0, stream>>>(P, IDX,
            CB[2], CG[2], CBE[2], CM[2], CV[2], H, 128);

        // ---- layer 3 ----
        xx_kernel<<<M/256, 256, 0, stream>>>(H, X, XX, 128, 128, 0);
        knn4_kernel<128><<<M/4, 256, 0, stream>>>(H, XX, IDX, 128);
        gemm_conv_kernel<<<(M/64)*4, 256, 0, stream>>>(H, CW[3], P, 128, 128, 256, 4);
        edge_epi_kernel<256><<<M, 256, 0, stream>>>(P, IDX,
            CB[3], CG[3], CBE[3], CM[3], CV[3], H, 256);

        lcpool_kernel<<<BB*8*16, 256, 0, stream>>>(H, LCW, LCB, LCG, LCBE, LCM, LCV, PMAX, PSUM);
        pool_reduce_kernel<<<BB*1024/256, 256, 0, stream>>>(PMAX, PSUM, H2);
        l0_kernel<<<(BB*512+255)/256, 256, 0, stream>>>(H2, L0W, L0G, L0BE, L0M, L0V, H3);
        l1_kernel<<<(BB*256+255)/256, 256, 0, stream>>>(H3, L1W, L1B, L1G, L1BE, L1M, L1V, H4);
        out_kernel<<<(BB*40+255)/256, 256, 0, stream>>>(H4, OW, OB, (float*)d_out);
    } else {
        xx_kernel<<<M/256, 256, 0, stream>>>(H, X, XX, 64, 0, 0);
        knn4_kernel<64><<<M/4, 256, 0, stream>>>(H, XX, IDX, 0);
        conv_kernel<64,64,false><<<M, 64, 0, stream>>>(H, X, IDX,
            CW[1], CB[1], CG[1], CBE[1], CM[1], CV[1], H, 0, 64);

        xx_kernel<<<M/256, 256, 0, stream>>>(H, X, XX, 64, 64, 0);
        knn4_kernel<64><<<M/4, 256, 0, stream>>>(H, XX, IDX, 64);
        conv_kernel<64,128,false><<<M, 128, 0, stream>>>(H, X, IDX,
            CW[2], CB[2], CG[2], CBE[2], CM[2], CV[2], H, 64, 128);

        xx_kernel<<<M/256, 256, 0, stream>>>(H, X, XX, 128, 128, 0);
        knn4_kernel<128><<<M/4, 256, 0, stream>>>(H, XX, IDX, 128);
        conv_kernel<128,256,false><<<M, 256, 0, stream>>>(H, X, IDX,
            CW[3], CB[3], CG[3], CBE[3], CM[3], CV[3], H, 128, 256);

        lcpool_kernel<<<BB*8*16, 256, 0, stream>>>(H, LCW, LCB, LCG, LCBE, LCM, LCV, fPMAX, fPSUM);
        pool_reduce_kernel<<<BB*1024/256, 256, 0, stream>>>(fPMAX, fPSUM, fH2);
        l0_kernel<<<(BB*512+255)/256, 256, 0, stream>>>(fH2, L0W, L0G, L0BE, L0M, L0V, fH3);
        l1_kernel<<<(BB*256+255)/256, 256, 0, stream>>>(fH3, L1W, L1B, L1G, L1BE, L1M, L1V, fH4);
        out_kernel<<<(BB*40+255)/256, 256, 0, stream>>>(fH4, OW, OB, (float*)d_out);
    }
}